// Round 3
// baseline (2408.533 us; speedup 1.0000x reference)
//
#include <hip/hip_runtime.h>

#define H_   512
#define T_   1000
#define B_   32
#define FIN_ 700
#define C_   50     // readout chunks
#define L_   20     // chunk length (C_*L_ == T_)
#define PF_  4      // wx prefetch depth (main-loop unroll)

static __device__ __forceinline__ float clampAlpha(float a) {
    const float AMIN = 0.8187307530779818f;   // exp(-1/5)
    const float AMAX = 0.9607894391523232f;   // exp(-1/25)
    return fminf(fmaxf(a, AMIN), AMAX);
}

// ------------------------------------------------------------------
// C[m,n] = sum_k A[m,k] * Bt[n,k]   (A: [M,K] row-major, Bt: [N,K])
// 64x64 tile, BK=16, 256 threads, 4x4 microtile per thread.
// ------------------------------------------------------------------
__global__ __launch_bounds__(256) void gemm_bt_kernel(
    const float* __restrict__ A, const float* __restrict__ Bt,
    float* __restrict__ C, int M, int N, int K)
{
    __shared__ __align__(16) float As[16][68];
    __shared__ __align__(16) float Bs[16][68];
    const int tid = threadIdx.x;
    const int bm = blockIdx.x * 64;
    const int bn = blockIdx.y * 64;
    const int tx = tid & 15, ty = tid >> 4;
    const int lrow = tid >> 2;          // 0..63
    const int lk   = (tid & 3) << 2;    // 0,4,8,12
    float acc[4][4] = {};
    const float* Arow = A + (size_t)(bm + lrow) * K;
    const float* Brow = Bt + (size_t)(bn + lrow) * K;

    for (int k0 = 0; k0 < K; k0 += 16) {
        const int ka = k0 + lk;
        float4 av, bv;
        if (ka + 3 < K) {
            av = *reinterpret_cast<const float4*>(Arow + ka);
            bv = *reinterpret_cast<const float4*>(Brow + ka);
        } else {
            float a_[4], b_[4];
            #pragma unroll
            for (int i = 0; i < 4; ++i) {
                a_[i] = (ka + i < K) ? Arow[ka + i] : 0.f;
                b_[i] = (ka + i < K) ? Brow[ka + i] : 0.f;
            }
            av = make_float4(a_[0], a_[1], a_[2], a_[3]);
            bv = make_float4(b_[0], b_[1], b_[2], b_[3]);
        }
        __syncthreads();
        As[lk + 0][lrow] = av.x; As[lk + 1][lrow] = av.y;
        As[lk + 2][lrow] = av.z; As[lk + 3][lrow] = av.w;
        Bs[lk + 0][lrow] = bv.x; Bs[lk + 1][lrow] = bv.y;
        Bs[lk + 2][lrow] = bv.z; Bs[lk + 3][lrow] = bv.w;
        __syncthreads();
        #pragma unroll
        for (int kk = 0; kk < 16; ++kk) {
            const float4 a4 = *reinterpret_cast<const float4*>(&As[kk][ty << 2]);
            const float4 b4 = *reinterpret_cast<const float4*>(&Bs[kk][tx << 2]);
            const float aa[4] = {a4.x, a4.y, a4.z, a4.w};
            const float bb[4] = {b4.x, b4.y, b4.z, b4.w};
            #pragma unroll
            for (int i = 0; i < 4; ++i)
                #pragma unroll
                for (int j = 0; j < 4; ++j)
                    acc[i][j] = fmaf(aa[i], bb[j], acc[i][j]);
        }
    }
    #pragma unroll
    for (int i = 0; i < 4; ++i) {
        const float4 r = make_float4(acc[i][0], acc[i][1], acc[i][2], acc[i][3]);
        *reinterpret_cast<float4*>(&C[(size_t)(bm + ty * 4 + i) * N + bn + tx * 4]) = r;
    }
}

// ------------------------------------------------------------------
// RLIF recurrence, one workgroup (512 threads, unit = tid) per batch.
//   - spike set as a 512-bit ballot mask in LDS, double-buffered
//   - ONE raw s_barrier per step (lgkmcnt only -- no vmcnt drain)
//   - wx register prefetch pipeline, depth PF_, so HBM latency hides
//     under PF_ steps of compute
// ------------------------------------------------------------------
__global__ __launch_bounds__(512) void rlif_kernel(
    const float* __restrict__ Wx,   // [B,T,H]
    const float* __restrict__ V,    // [H,H]
    const float* __restrict__ alpha,// [H]
    const float* __restrict__ ut0,  // [B,H]
    const float* __restrict__ st0,  // [B,H]
    float* __restrict__ s_out,      // [B,T,H]
    float* __restrict__ fire)       // [B,H] spike counts
{
    const int b    = blockIdx.x;
    const int tid  = threadIdx.x;       // unit index 0..511
    const int wid  = tid >> 6;          // wave 0..7
    const int lane = tid & 63;
    __shared__ unsigned long long mask_lds[2][8];
    __shared__ float st0_sh[H_];

    const float a  = clampAlpha(alpha[tid]);
    const float om = 1.f - a;
    const float vd = V[(size_t)tid * H_ + tid];
    float u = ut0[b * H_ + tid];
    float s = st0[b * H_ + tid];
    float f = 0.f;
    const float* wxb = Wx + (size_t)b * T_ * H_;
    float*       sob = s_out + (size_t)b * T_ * H_;

    // prologue: zero both mask buffers, stage st0 row, dense t=0 gather
    if (tid < 16) ((unsigned long long*)mask_lds)[tid] = 0ULL;
    st0_sh[tid] = st0[b * H_ + tid];
    __syncthreads();

    float rec_pre = 0.f;
    #pragma unroll 8
    for (int h = 0; h < H_; ++h)
        rec_pre = fmaf(st0_sh[h], V[(size_t)h * H_ + tid], rec_pre);

    // wx prefetch pipeline
    float wxp[PF_];
    #pragma unroll
    for (int i = 0; i < PF_; ++i)
        wxp[i] = wxb[(size_t)i * H_ + tid];

    int p = 0;
    for (int g = 0; g < T_ / PF_; ++g) {
        #pragma unroll
        for (int i = 0; i < PF_; ++i) {
            const int t = g * PF_ + i;
            const float wx = wxp[i];                    // loaded PF_ steps ago
            if (t + PF_ < T_)
                wxp[i] = wxb[(size_t)(t + PF_) * H_ + tid];

            // gather rec over the active mask (uniform scalar bit-scan)
            float rec = 0.f;
            #pragma unroll
            for (int w = 0; w < 8; ++w) {
                const unsigned long long mw = mask_lds[p][w];
                const unsigned mlo = __builtin_amdgcn_readfirstlane((unsigned)mw);
                const unsigned mhi = __builtin_amdgcn_readfirstlane((unsigned)(mw >> 32));
                unsigned long long m = ((unsigned long long)mhi << 32) | mlo;
                const float* rowp = V + ((size_t)(w << 6)) * H_ + tid;
                while (m) {
                    const int bb = __builtin_ctzll(m);
                    m &= (m - 1);
                    rec += rowp[(size_t)bb * H_];
                }
            }
            if (t == 0) rec = rec_pre;     // t=0 mask is empty; dense pre-pass
            rec -= s * vd;                 // zero-diagonal correction
            u = a * (u - s) + om * (wx + rec);
            s = (u > 1.f) ? 1.f : 0.f;
            f += s;
            sob[(size_t)t * H_ + tid] = s;

            const unsigned long long bal = __ballot(u > 1.f);
            if (lane == 0) mask_lds[p ^ 1][wid] = bal;

            // publish mask; do NOT drain vmcnt (prefetch stays in flight)
            asm volatile("s_waitcnt lgkmcnt(0)" ::: "memory");
            __builtin_amdgcn_s_barrier();
            __builtin_amdgcn_sched_barrier(0);
            p ^= 1;
        }
    }
    fire[b * H_ + tid] = f;
}

// ------------------------------------------------------------------
// Readout, parallel-scan decomposition over T.
// ------------------------------------------------------------------
__global__ __launch_bounds__(256) void ro_partial_kernel(
    const float* __restrict__ Wx,    // [B,T,H]
    const float* __restrict__ alpha,
    float* __restrict__ u_end)       // [B,C,H]
{
    const int b = blockIdx.x;
    const int c = blockIdx.y;
    const int j0 = threadIdx.x * 2;
    const float a0 = clampAlpha(alpha[j0]);
    const float a1 = clampAlpha(alpha[j0 + 1]);
    const float om0 = 1.f - a0, om1 = 1.f - a1;
    float u0 = 0.f, u1 = 0.f;
    const float* wxb = Wx + ((size_t)b * T_ + (size_t)c * L_) * H_;
    #pragma unroll 4
    for (int t = 0; t < L_; ++t) {
        const float2 wx = *reinterpret_cast<const float2*>(&wxb[(size_t)t * H_ + j0]);
        u0 = fmaf(a0, u0, om0 * wx.x);
        u1 = fmaf(a1, u1, om1 * wx.y);
    }
    float* ue = u_end + ((size_t)b * C_ + c) * H_;
    *reinterpret_cast<float2*>(&ue[j0]) = make_float2(u0, u1);
}

__global__ __launch_bounds__(256) void ro_carry_kernel(
    const float* __restrict__ u_end, // [B,C,H]
    const float* __restrict__ alpha,
    const float* __restrict__ ut0,   // [B,H]
    float* __restrict__ carry)       // [B,C,H]
{
    const int b = blockIdx.x;
    const int j0 = threadIdx.x * 2;
    const float a0 = clampAlpha(alpha[j0]);
    const float a1 = clampAlpha(alpha[j0 + 1]);
    const float aL0 = powf(a0, (float)L_);
    const float aL1 = powf(a1, (float)L_);
    float c0 = ut0[b * H_ + j0];
    float c1 = ut0[b * H_ + j0 + 1];
    for (int c = 0; c < C_; ++c) {
        float* cr = carry + ((size_t)b * C_ + c) * H_;
        *reinterpret_cast<float2*>(&cr[j0]) = make_float2(c0, c1);
        const float2 ue = *reinterpret_cast<const float2*>(
            &u_end[((size_t)b * C_ + c) * H_ + j0]);
        c0 = fmaf(aL0, c0, ue.x);
        c1 = fmaf(aL1, c1, ue.y);
    }
}

__global__ __launch_bounds__(256) void ro_softmax_kernel(
    const float* __restrict__ Wx,    // [B,T,H]
    const float* __restrict__ alpha,
    const float* __restrict__ carry, // [B,C,H]
    float* __restrict__ opart)       // [C,B,H]
{
    const int b = blockIdx.x;
    const int c = blockIdx.y;
    const int tid = threadIdx.x;
    const int j0 = tid * 2;
    __shared__ float red[8];
    const float a0 = clampAlpha(alpha[j0]);
    const float a1 = clampAlpha(alpha[j0 + 1]);
    const float om0 = 1.f - a0, om1 = 1.f - a1;
    float2 u = *reinterpret_cast<const float2*>(
        &carry[((size_t)b * C_ + c) * H_ + j0]);
    float u0 = u.x, u1 = u.y;
    float o0 = 0.f, o1 = 0.f;
    const float* wxb = Wx + ((size_t)b * T_ + (size_t)c * L_) * H_;
    const int wave = tid >> 6;
    const int lane = tid & 63;

    for (int t = 0; t < L_; ++t) {
        const float2 wx = *reinterpret_cast<const float2*>(&wxb[(size_t)t * H_ + j0]);
        u0 = fmaf(a0, u0, om0 * wx.x);
        u1 = fmaf(a1, u1, om1 * wx.y);
        float m = fmaxf(u0, u1);
        #pragma unroll
        for (int off = 32; off > 0; off >>= 1)
            m = fmaxf(m, __shfl_xor(m, off, 64));
        if (lane == 0) red[wave] = m;
        __syncthreads();
        m = fmaxf(fmaxf(red[0], red[1]), fmaxf(red[2], red[3]));
        const float e0 = expf(u0 - m), e1 = expf(u1 - m);
        float sum = e0 + e1;
        #pragma unroll
        for (int off = 32; off > 0; off >>= 1)
            sum += __shfl_xor(sum, off, 64);
        if (lane == 0) red[4 + wave] = sum;
        __syncthreads();
        sum = (red[4] + red[5]) + (red[6] + red[7]);
        const float inv = 1.f / sum;
        o0 = fmaf(e0, inv, o0);
        o1 = fmaf(e1, inv, o1);
        __syncthreads();
    }
    float* op = opart + ((size_t)c * B_ + b) * H_;
    *reinterpret_cast<float2*>(&op[j0]) = make_float2(o0, o1);
}

__global__ __launch_bounds__(256) void ro_reduce_kernel(
    const float* __restrict__ opart, float* __restrict__ out)
{
    const int idx = blockIdx.x * 256 + threadIdx.x;  // 0 .. B*H-1
    float s = 0.f;
    for (int c = 0; c < C_; ++c) s += opart[(size_t)c * B_ * H_ + idx];
    out[idx] = s;
}

__global__ __launch_bounds__(256) void fire_reduce_kernel(
    const float* __restrict__ fire, float* __restrict__ out)
{
    const int h = blockIdx.x * 256 + threadIdx.x;
    if (h >= H_) return;
    const float inv = 1.f / (float)(B_ * T_);
    float s = 0.f;
    for (int b = 0; b < B_; ++b) s += fire[b * H_ + h];
    out[h] = s * inv;
    s = 0.f;
    for (int b = 0; b < B_; ++b) s += fire[B_ * H_ + b * H_ + h];
    out[H_ + h] = s * inv;
}

extern "C" void kernel_launch(void* const* d_in, const int* in_sizes, int n_in,
                              void* d_out, int out_size, void* d_ws, size_t ws_size,
                              hipStream_t stream)
{
    const float* x      = (const float*)d_in[0];
    const float* W0     = (const float*)d_in[1];
    const float* V0     = (const float*)d_in[2];
    const float* alpha0 = (const float*)d_in[3];
    const float* W1     = (const float*)d_in[4];
    const float* V1     = (const float*)d_in[5];
    const float* alpha1 = (const float*)d_in[6];
    const float* Wr     = (const float*)d_in[7];
    const float* alphar = (const float*)d_in[8];
    const float* ut0_0  = (const float*)d_in[9];
    const float* st0_0  = (const float*)d_in[10];
    const float* ut0_1  = (const float*)d_in[11];
    const float* st0_1  = (const float*)d_in[12];
    const float* ut0_r  = (const float*)d_in[13];
    float* out = (float*)d_out;

    const size_t NBTH = (size_t)B_ * T_ * H_;
    const size_t NBCH = (size_t)B_ * C_ * H_;
    float* buf0  = (float*)d_ws;          // Wx0 -> Wx1 -> Wxr
    float* buf1  = buf0 + NBTH;           // s0  -> s1
    float* fire  = buf1 + NBTH;           // [2, B, H]
    float* u_end = fire + 2 * B_ * H_;    // [B, C, H]
    float* carry = u_end + NBCH;          // [B, C, H]
    float* opart = carry + NBCH;          // [C, B, H]

    dim3 gG(32000 / 64, 512 / 64);
    // Wx0 = x @ W0^T
    gemm_bt_kernel<<<gG, 256, 0, stream>>>(x, W0, buf0, 32000, 512, 700);
    // s0 = RLIF(Wx0, V0)
    rlif_kernel<<<32, 512, 0, stream>>>(buf0, V0, alpha0, ut0_0, st0_0, buf1, fire);
    // Wx1 = s0 @ W1^T
    gemm_bt_kernel<<<gG, 256, 0, stream>>>(buf1, W1, buf0, 32000, 512, 512);
    // s1 = RLIF(Wx1, V1)
    rlif_kernel<<<32, 512, 0, stream>>>(buf0, V1, alpha1, ut0_1, st0_1, buf1, fire + B_ * H_);
    // Wxr = s1 @ Wr^T
    gemm_bt_kernel<<<gG, 256, 0, stream>>>(buf1, Wr, buf0, 32000, 512, 512);
    // Readout: parallel scan + softmax partials + reduce
    ro_partial_kernel<<<dim3(B_, C_), 256, 0, stream>>>(buf0, alphar, u_end);
    ro_carry_kernel<<<B_, 256, 0, stream>>>(u_end, alphar, ut0_r, carry);
    ro_softmax_kernel<<<dim3(B_, C_), 256, 0, stream>>>(buf0, alphar, carry, opart);
    ro_reduce_kernel<<<(B_ * H_) / 256, 256, 0, stream>>>(opart, out);
    // firing rates
    fire_reduce_kernel<<<2, 256, 0, stream>>>(fire, out + B_ * H_);
}

// Round 4
// 1823.460 us; speedup vs baseline: 1.3209x; 1.3209x over previous
//
#include <hip/hip_runtime.h>

#define H_   512
#define T_   1000
#define B_   32
#define FIN_ 700
#define C_   50     // readout chunks
#define L_   20     // chunk length (C_*L_ == T_)
#define PF_  4      // wx prefetch depth

static __device__ __forceinline__ float clampAlpha(float a) {
    const float AMIN = 0.8187307530779818f;   // exp(-1/5)
    const float AMAX = 0.9607894391523232f;   // exp(-1/25)
    return fminf(fmaxf(a, AMIN), AMAX);
}

// ------------------------------------------------------------------
// C[m,n] = sum_k A[m,k] * Bt[n,k]   (A: [M,K] row-major, Bt: [N,K])
// ------------------------------------------------------------------
__global__ __launch_bounds__(256) void gemm_bt_kernel(
    const float* __restrict__ A, const float* __restrict__ Bt,
    float* __restrict__ C, int M, int N, int K)
{
    __shared__ __align__(16) float As[16][68];
    __shared__ __align__(16) float Bs[16][68];
    const int tid = threadIdx.x;
    const int bm = blockIdx.x * 64;
    const int bn = blockIdx.y * 64;
    const int tx = tid & 15, ty = tid >> 4;
    const int lrow = tid >> 2;          // 0..63
    const int lk   = (tid & 3) << 2;    // 0,4,8,12
    float acc[4][4] = {};
    const float* Arow = A + (size_t)(bm + lrow) * K;
    const float* Brow = Bt + (size_t)(bn + lrow) * K;

    for (int k0 = 0; k0 < K; k0 += 16) {
        const int ka = k0 + lk;
        float4 av, bv;
        if (ka + 3 < K) {
            av = *reinterpret_cast<const float4*>(Arow + ka);
            bv = *reinterpret_cast<const float4*>(Brow + ka);
        } else {
            float a_[4], b_[4];
            #pragma unroll
            for (int i = 0; i < 4; ++i) {
                a_[i] = (ka + i < K) ? Arow[ka + i] : 0.f;
                b_[i] = (ka + i < K) ? Brow[ka + i] : 0.f;
            }
            av = make_float4(a_[0], a_[1], a_[2], a_[3]);
            bv = make_float4(b_[0], b_[1], b_[2], b_[3]);
        }
        __syncthreads();
        As[lk + 0][lrow] = av.x; As[lk + 1][lrow] = av.y;
        As[lk + 2][lrow] = av.z; As[lk + 3][lrow] = av.w;
        Bs[lk + 0][lrow] = bv.x; Bs[lk + 1][lrow] = bv.y;
        Bs[lk + 2][lrow] = bv.z; Bs[lk + 3][lrow] = bv.w;
        __syncthreads();
        #pragma unroll
        for (int kk = 0; kk < 16; ++kk) {
            const float4 a4 = *reinterpret_cast<const float4*>(&As[kk][ty << 2]);
            const float4 b4 = *reinterpret_cast<const float4*>(&Bs[kk][tx << 2]);
            const float aa[4] = {a4.x, a4.y, a4.z, a4.w};
            const float bb[4] = {b4.x, b4.y, b4.z, b4.w};
            #pragma unroll
            for (int i = 0; i < 4; ++i)
                #pragma unroll
                for (int j = 0; j < 4; ++j)
                    acc[i][j] = fmaf(aa[i], bb[j], acc[i][j]);
        }
    }
    #pragma unroll
    for (int i = 0; i < 4; ++i) {
        const float4 r = make_float4(acc[i][0], acc[i][1], acc[i][2], acc[i][3]);
        *reinterpret_cast<float4*>(&C[(size_t)(bm + ty * 4 + i) * N + bn + tx * 4]) = r;
    }
}

// ------------------------------------------------------------------
// RLIF v4: 256 threads/batch, 2 units/thread.
//  - active list double-buffered in LDS, built by ballot-prefix
//    (per-wave 128-entry segments, no atomics)
//  - gather: int4 LDS index reads (ds_read_b128 broadcast) + 4
//    independent float2 V loads per batch -> >=4 loads in flight
//  - ONE raw s_barrier per step (lgkmcnt-only; vmcnt stays in flight)
//  - wx register prefetch pipeline depth PF_
// ------------------------------------------------------------------
__global__ __launch_bounds__(256) void rlif_kernel(
    const float* __restrict__ Wx,   // [B,T,H]
    const float* __restrict__ V,    // [H,H]
    const float* __restrict__ alpha,// [H]
    const float* __restrict__ ut0,  // [B,H]
    const float* __restrict__ st0,  // [B,H]
    float* __restrict__ s_out,      // [B,T,H]
    float* __restrict__ fire)       // [B,H] spike counts
{
    const int b    = blockIdx.x;
    const int tid  = threadIdx.x;       // 0..255
    const int j0   = tid * 2;           // unit pair
    const int wid  = tid >> 6;          // wave 0..3
    const int lane = tid & 63;
    __shared__ __align__(16) int act[2][4][132];   // [buf][wave-seg][entries]
    __shared__ int cnt[2][4];
    __shared__ float st0_sh[H_];

    const float a0 = clampAlpha(alpha[j0]);
    const float a1 = clampAlpha(alpha[j0 + 1]);
    const float om0 = 1.f - a0, om1 = 1.f - a1;
    const float vd0 = V[(size_t)j0 * H_ + j0];
    const float vd1 = V[(size_t)(j0 + 1) * H_ + (j0 + 1)];
    float u0 = ut0[b * H_ + j0], u1 = ut0[b * H_ + j0 + 1];
    float s0 = st0[b * H_ + j0], s1 = st0[b * H_ + j0 + 1];
    float f0 = 0.f, f1 = 0.f;
    const float* wxb = Wx + (size_t)b * T_ * H_;
    float*       sob = s_out + (size_t)b * T_ * H_;

    // prologue
    if (tid < 8) ((int*)cnt)[tid] = 0;
    st0_sh[j0]     = st0[b * H_ + j0];
    st0_sh[j0 + 1] = st0[b * H_ + j0 + 1];
    __syncthreads();

    // dense t=0 recurrent input (st0 is real-valued)
    float pre0 = 0.f, pre1 = 0.f;
    #pragma unroll 8
    for (int h = 0; h < H_; ++h) {
        const float s = st0_sh[h];
        const float2 v = *reinterpret_cast<const float2*>(&V[(size_t)h * H_ + j0]);
        pre0 = fmaf(s, v.x, pre0);
        pre1 = fmaf(s, v.y, pre1);
    }

    // wx prefetch pipeline
    float2 wxp[PF_];
    #pragma unroll
    for (int i = 0; i < PF_; ++i)
        wxp[i] = *reinterpret_cast<const float2*>(&wxb[(size_t)i * H_ + j0]);

    int p = 0;
    for (int g = 0; g < T_ / PF_; ++g) {
        #pragma unroll
        for (int i = 0; i < PF_; ++i) {
            const int t = g * PF_ + i;
            const float2 wx = wxp[i];
            if (t + PF_ < T_)
                wxp[i] = *reinterpret_cast<const float2*>(&wxb[(size_t)(t + PF_) * H_ + j0]);

            // ---- gather over previous step's active list ----
            float rec0 = 0.f, rec1 = 0.f;
            #pragma unroll
            for (int seg = 0; seg < 4; ++seg) {
                const int n = __builtin_amdgcn_readfirstlane(cnt[p][seg]);
                const int* ap = &act[p][seg][0];
                int k = 0;
                for (; k + 4 <= n; k += 4) {
                    const int4 h4 = *reinterpret_cast<const int4*>(ap + k); // b128 broadcast
                    const float2 v0 = *reinterpret_cast<const float2*>(&V[(size_t)h4.x * H_ + j0]);
                    const float2 v1 = *reinterpret_cast<const float2*>(&V[(size_t)h4.y * H_ + j0]);
                    const float2 v2 = *reinterpret_cast<const float2*>(&V[(size_t)h4.z * H_ + j0]);
                    const float2 v3 = *reinterpret_cast<const float2*>(&V[(size_t)h4.w * H_ + j0]);
                    rec0 += (v0.x + v1.x) + (v2.x + v3.x);
                    rec1 += (v0.y + v1.y) + (v2.y + v3.y);
                }
                for (; k < n; ++k) {
                    const float2 v = *reinterpret_cast<const float2*>(&V[(size_t)ap[k] * H_ + j0]);
                    rec0 += v.x; rec1 += v.y;
                }
            }
            if (t == 0) { rec0 = pre0; rec1 = pre1; }
            rec0 -= s0 * vd0;               // zero-diagonal correction
            rec1 -= s1 * vd1;

            u0 = a0 * (u0 - s0) + om0 * (wx.x + rec0);
            u1 = a1 * (u1 - s1) + om1 * (wx.y + rec1);
            s0 = (u0 > 1.f) ? 1.f : 0.f;
            s1 = (u1 > 1.f) ? 1.f : 0.f;
            f0 += s0; f1 += s1;
            *reinterpret_cast<float2*>(&sob[(size_t)t * H_ + j0]) = make_float2(s0, s1);

            // ---- build next step's list (ballot prefix, no atomics) ----
            const unsigned long long bal0 = __ballot(u0 > 1.f);
            const unsigned long long bal1 = __ballot(u1 > 1.f);
            const unsigned long long lt = (lane == 63) ? 0x7FFFFFFFFFFFFFFFULL
                                                       : ((1ULL << lane) - 1ULL);
            int k = (int)__popcll(bal0 & lt) + (int)__popcll(bal1 & lt);
            int* seg = &act[p ^ 1][wid][0];
            if (s0 != 0.f) { seg[k] = j0; ++k; }
            if (s1 != 0.f) { seg[k] = j0 + 1; }
            if (lane == 0) cnt[p ^ 1][wid] = (int)__popcll(bal0) + (int)__popcll(bal1);

            asm volatile("s_waitcnt lgkmcnt(0)" ::: "memory");
            __builtin_amdgcn_s_barrier();
            __builtin_amdgcn_sched_barrier(0);
            p ^= 1;
        }
    }
    fire[b * H_ + j0]     = f0;
    fire[b * H_ + j0 + 1] = f1;
}

// ------------------------------------------------------------------
// Readout, parallel-scan decomposition over T.
// ------------------------------------------------------------------
__global__ __launch_bounds__(256) void ro_partial_kernel(
    const float* __restrict__ Wx,    // [B,T,H]
    const float* __restrict__ alpha,
    float* __restrict__ u_end)       // [B,C,H]
{
    const int b = blockIdx.x;
    const int c = blockIdx.y;
    const int j0 = threadIdx.x * 2;
    const float a0 = clampAlpha(alpha[j0]);
    const float a1 = clampAlpha(alpha[j0 + 1]);
    const float om0 = 1.f - a0, om1 = 1.f - a1;
    float u0 = 0.f, u1 = 0.f;
    const float* wxb = Wx + ((size_t)b * T_ + (size_t)c * L_) * H_;
    #pragma unroll 4
    for (int t = 0; t < L_; ++t) {
        const float2 wx = *reinterpret_cast<const float2*>(&wxb[(size_t)t * H_ + j0]);
        u0 = fmaf(a0, u0, om0 * wx.x);
        u1 = fmaf(a1, u1, om1 * wx.y);
    }
    float* ue = u_end + ((size_t)b * C_ + c) * H_;
    *reinterpret_cast<float2*>(&ue[j0]) = make_float2(u0, u1);
}

__global__ __launch_bounds__(256) void ro_carry_kernel(
    const float* __restrict__ u_end, // [B,C,H]
    const float* __restrict__ alpha,
    const float* __restrict__ ut0,   // [B,H]
    float* __restrict__ carry)       // [B,C,H]
{
    const int b = blockIdx.x;
    const int j0 = threadIdx.x * 2;
    const float a0 = clampAlpha(alpha[j0]);
    const float a1 = clampAlpha(alpha[j0 + 1]);
    const float aL0 = powf(a0, (float)L_);
    const float aL1 = powf(a1, (float)L_);
    float c0 = ut0[b * H_ + j0];
    float c1 = ut0[b * H_ + j0 + 1];
    for (int c = 0; c < C_; ++c) {
        float* cr = carry + ((size_t)b * C_ + c) * H_;
        *reinterpret_cast<float2*>(&cr[j0]) = make_float2(c0, c1);
        const float2 ue = *reinterpret_cast<const float2*>(
            &u_end[((size_t)b * C_ + c) * H_ + j0]);
        c0 = fmaf(aL0, c0, ue.x);
        c1 = fmaf(aL1, c1, ue.y);
    }
}

__global__ __launch_bounds__(256) void ro_softmax_kernel(
    const float* __restrict__ Wx,    // [B,T,H]
    const float* __restrict__ alpha,
    const float* __restrict__ carry, // [B,C,H]
    float* __restrict__ opart)       // [C,B,H]
{
    const int b = blockIdx.x;
    const int c = blockIdx.y;
    const int tid = threadIdx.x;
    const int j0 = tid * 2;
    __shared__ float red[8];
    const float a0 = clampAlpha(alpha[j0]);
    const float a1 = clampAlpha(alpha[j0 + 1]);
    const float om0 = 1.f - a0, om1 = 1.f - a1;
    float2 u = *reinterpret_cast<const float2*>(
        &carry[((size_t)b * C_ + c) * H_ + j0]);
    float u0 = u.x, u1 = u.y;
    float o0 = 0.f, o1 = 0.f;
    const float* wxb = Wx + ((size_t)b * T_ + (size_t)c * L_) * H_;
    const int wave = tid >> 6;
    const int lane = tid & 63;

    for (int t = 0; t < L_; ++t) {
        const float2 wx = *reinterpret_cast<const float2*>(&wxb[(size_t)t * H_ + j0]);
        u0 = fmaf(a0, u0, om0 * wx.x);
        u1 = fmaf(a1, u1, om1 * wx.y);
        float m = fmaxf(u0, u1);
        #pragma unroll
        for (int off = 32; off > 0; off >>= 1)
            m = fmaxf(m, __shfl_xor(m, off, 64));
        if (lane == 0) red[wave] = m;
        __syncthreads();
        m = fmaxf(fmaxf(red[0], red[1]), fmaxf(red[2], red[3]));
        const float e0 = expf(u0 - m), e1 = expf(u1 - m);
        float sum = e0 + e1;
        #pragma unroll
        for (int off = 32; off > 0; off >>= 1)
            sum += __shfl_xor(sum, off, 64);
        if (lane == 0) red[4 + wave] = sum;
        __syncthreads();
        sum = (red[4] + red[5]) + (red[6] + red[7]);
        const float inv = 1.f / sum;
        o0 = fmaf(e0, inv, o0);
        o1 = fmaf(e1, inv, o1);
        __syncthreads();
    }
    float* op = opart + ((size_t)c * B_ + b) * H_;
    *reinterpret_cast<float2*>(&op[j0]) = make_float2(o0, o1);
}

__global__ __launch_bounds__(256) void ro_reduce_kernel(
    const float* __restrict__ opart, float* __restrict__ out)
{
    const int idx = blockIdx.x * 256 + threadIdx.x;  // 0 .. B*H-1
    float s = 0.f;
    for (int c = 0; c < C_; ++c) s += opart[(size_t)c * B_ * H_ + idx];
    out[idx] = s;
}

__global__ __launch_bounds__(256) void fire_reduce_kernel(
    const float* __restrict__ fire, float* __restrict__ out)
{
    const int h = blockIdx.x * 256 + threadIdx.x;
    if (h >= H_) return;
    const float inv = 1.f / (float)(B_ * T_);
    float s = 0.f;
    for (int b = 0; b < B_; ++b) s += fire[b * H_ + h];
    out[h] = s * inv;
    s = 0.f;
    for (int b = 0; b < B_; ++b) s += fire[B_ * H_ + b * H_ + h];
    out[H_ + h] = s * inv;
}

extern "C" void kernel_launch(void* const* d_in, const int* in_sizes, int n_in,
                              void* d_out, int out_size, void* d_ws, size_t ws_size,
                              hipStream_t stream)
{
    const float* x      = (const float*)d_in[0];
    const float* W0     = (const float*)d_in[1];
    const float* V0     = (const float*)d_in[2];
    const float* alpha0 = (const float*)d_in[3];
    const float* W1     = (const float*)d_in[4];
    const float* V1     = (const float*)d_in[5];
    const float* alpha1 = (const float*)d_in[6];
    const float* Wr     = (const float*)d_in[7];
    const float* alphar = (const float*)d_in[8];
    const float* ut0_0  = (const float*)d_in[9];
    const float* st0_0  = (const float*)d_in[10];
    const float* ut0_1  = (const float*)d_in[11];
    const float* st0_1  = (const float*)d_in[12];
    const float* ut0_r  = (const float*)d_in[13];
    float* out = (float*)d_out;

    const size_t NBTH = (size_t)B_ * T_ * H_;
    const size_t NBCH = (size_t)B_ * C_ * H_;
    float* buf0  = (float*)d_ws;          // Wx0 -> Wx1 -> Wxr
    float* buf1  = buf0 + NBTH;           // s0  -> s1
    float* fire  = buf1 + NBTH;           // [2, B, H]
    float* u_end = fire + 2 * B_ * H_;    // [B, C, H]
    float* carry = u_end + NBCH;          // [B, C, H]
    float* opart = carry + NBCH;          // [C, B, H]

    dim3 gG(32000 / 64, 512 / 64);
    // Wx0 = x @ W0^T
    gemm_bt_kernel<<<gG, 256, 0, stream>>>(x, W0, buf0, 32000, 512, 700);
    // s0 = RLIF(Wx0, V0)
    rlif_kernel<<<32, 256, 0, stream>>>(buf0, V0, alpha0, ut0_0, st0_0, buf1, fire);
    // Wx1 = s0 @ W1^T
    gemm_bt_kernel<<<gG, 256, 0, stream>>>(buf1, W1, buf0, 32000, 512, 512);
    // s1 = RLIF(Wx1, V1)
    rlif_kernel<<<32, 256, 0, stream>>>(buf0, V1, alpha1, ut0_1, st0_1, buf1, fire + B_ * H_);
    // Wxr = s1 @ Wr^T
    gemm_bt_kernel<<<gG, 256, 0, stream>>>(buf1, Wr, buf0, 32000, 512, 512);
    // Readout: parallel scan + softmax partials + reduce
    ro_partial_kernel<<<dim3(B_, C_), 256, 0, stream>>>(buf0, alphar, u_end);
    ro_carry_kernel<<<B_, 256, 0, stream>>>(u_end, alphar, ut0_r, carry);
    ro_softmax_kernel<<<dim3(B_, C_), 256, 0, stream>>>(buf0, alphar, carry, opart);
    ro_reduce_kernel<<<(B_ * H_) / 256, 256, 0, stream>>>(opart, out);
    // firing rates
    fire_reduce_kernel<<<2, 256, 0, stream>>>(fire, out + B_ * H_);
}

// Round 5
// 1747.749 us; speedup vs baseline: 1.3781x; 1.0433x over previous
//
#include <hip/hip_runtime.h>

#define H_   512
#define T_   1000
#define B_   32
#define FIN_ 700
#define C_   50     // readout chunks
#define L_   20     // chunk length (C_*L_ == T_)
#define PF_  4      // wx prefetch depth

typedef _Float16 h2v __attribute__((ext_vector_type(2)));
typedef _Float16 h4v __attribute__((ext_vector_type(4)));

static __device__ __forceinline__ float clampAlpha(float a) {
    const float AMIN = 0.8187307530779818f;   // exp(-1/5)
    const float AMAX = 0.9607894391523232f;   // exp(-1/25)
    return fminf(fmaxf(a, AMIN), AMAX);
}

// ------------------------------------------------------------------
// fp32 -> fp16 conversion for V (1 MB -> 512 KB), 4 elems/thread
// ------------------------------------------------------------------
__global__ __launch_bounds__(256) void vconv_kernel(
    const float* __restrict__ V, _Float16* __restrict__ Vh)
{
    const int i = (blockIdx.x * 256 + threadIdx.x) * 4;
    const float4 v = *reinterpret_cast<const float4*>(V + i);
    h4v o;
    o.x = (_Float16)v.x; o.y = (_Float16)v.y;
    o.z = (_Float16)v.z; o.w = (_Float16)v.w;
    *reinterpret_cast<h4v*>(Vh + i) = o;
}

// ------------------------------------------------------------------
// C[m,n] = sum_k A[m,k] * Bt[n,k]   (A: [M,K] row-major, Bt: [N,K])
// ------------------------------------------------------------------
__global__ __launch_bounds__(256) void gemm_bt_kernel(
    const float* __restrict__ A, const float* __restrict__ Bt,
    float* __restrict__ C, int M, int N, int K)
{
    __shared__ __align__(16) float As[16][68];
    __shared__ __align__(16) float Bs[16][68];
    const int tid = threadIdx.x;
    const int bm = blockIdx.x * 64;
    const int bn = blockIdx.y * 64;
    const int tx = tid & 15, ty = tid >> 4;
    const int lrow = tid >> 2;          // 0..63
    const int lk   = (tid & 3) << 2;    // 0,4,8,12
    float acc[4][4] = {};
    const float* Arow = A + (size_t)(bm + lrow) * K;
    const float* Brow = Bt + (size_t)(bn + lrow) * K;

    for (int k0 = 0; k0 < K; k0 += 16) {
        const int ka = k0 + lk;
        float4 av, bv;
        if (ka + 3 < K) {
            av = *reinterpret_cast<const float4*>(Arow + ka);
            bv = *reinterpret_cast<const float4*>(Brow + ka);
        } else {
            float a_[4], b_[4];
            #pragma unroll
            for (int i = 0; i < 4; ++i) {
                a_[i] = (ka + i < K) ? Arow[ka + i] : 0.f;
                b_[i] = (ka + i < K) ? Brow[ka + i] : 0.f;
            }
            av = make_float4(a_[0], a_[1], a_[2], a_[3]);
            bv = make_float4(b_[0], b_[1], b_[2], b_[3]);
        }
        __syncthreads();
        As[lk + 0][lrow] = av.x; As[lk + 1][lrow] = av.y;
        As[lk + 2][lrow] = av.z; As[lk + 3][lrow] = av.w;
        Bs[lk + 0][lrow] = bv.x; Bs[lk + 1][lrow] = bv.y;
        Bs[lk + 2][lrow] = bv.z; Bs[lk + 3][lrow] = bv.w;
        __syncthreads();
        #pragma unroll
        for (int kk = 0; kk < 16; ++kk) {
            const float4 a4 = *reinterpret_cast<const float4*>(&As[kk][ty << 2]);
            const float4 b4 = *reinterpret_cast<const float4*>(&Bs[kk][tx << 2]);
            const float aa[4] = {a4.x, a4.y, a4.z, a4.w};
            const float bb[4] = {b4.x, b4.y, b4.z, b4.w};
            #pragma unroll
            for (int i = 0; i < 4; ++i)
                #pragma unroll
                for (int j = 0; j < 4; ++j)
                    acc[i][j] = fmaf(aa[i], bb[j], acc[i][j]);
        }
    }
    #pragma unroll
    for (int i = 0; i < 4; ++i) {
        const float4 r = make_float4(acc[i][0], acc[i][1], acc[i][2], acc[i][3]);
        *reinterpret_cast<float4*>(&C[(size_t)(bm + ty * 4 + i) * N + bn + tx * 4]) = r;
    }
}

// ------------------------------------------------------------------
// RLIF v5: 256 threads/batch, 2 units/thread; V gathered in fp16
// (halves the per-CU L2 traffic that bounds this kernel).
//  - active list double-buffered in LDS (ballot-prefix, no atomics)
//  - int4 LDS index reads + 4 independent fp16x2 V loads in flight
//  - ONE raw s_barrier per step (lgkmcnt-only; vmcnt stays in flight)
//  - wx register prefetch pipeline depth PF_
// Diagonal correction + t=0 dense pass use the SAME fp16 values, so
// the zero-diagonal identity is exact.
// ------------------------------------------------------------------
__global__ __launch_bounds__(256) void rlif_kernel(
    const float* __restrict__ Wx,   // [B,T,H]
    const _Float16* __restrict__ Vh,// [H,H] fp16
    const float* __restrict__ alpha,// [H]
    const float* __restrict__ ut0,  // [B,H]
    const float* __restrict__ st0,  // [B,H]
    float* __restrict__ s_out,      // [B,T,H]
    float* __restrict__ fire)       // [B,H] spike counts
{
    const int b    = blockIdx.x;
    const int tid  = threadIdx.x;       // 0..255
    const int j0   = tid * 2;           // unit pair
    const int wid  = tid >> 6;          // wave 0..3
    const int lane = tid & 63;
    __shared__ __align__(16) int act[2][4][132];   // [buf][wave-seg][entries]
    __shared__ int cnt[2][4];
    __shared__ float st0_sh[H_];

    const float a0 = clampAlpha(alpha[j0]);
    const float a1 = clampAlpha(alpha[j0 + 1]);
    const float om0 = 1.f - a0, om1 = 1.f - a1;
    const float vd0 = (float)Vh[(size_t)j0 * H_ + j0];
    const float vd1 = (float)Vh[(size_t)(j0 + 1) * H_ + (j0 + 1)];
    float u0 = ut0[b * H_ + j0], u1 = ut0[b * H_ + j0 + 1];
    float s0 = st0[b * H_ + j0], s1 = st0[b * H_ + j0 + 1];
    float f0 = 0.f, f1 = 0.f;
    const float* wxb = Wx + (size_t)b * T_ * H_;
    float*       sob = s_out + (size_t)b * T_ * H_;

    // prologue
    if (tid < 8) ((int*)cnt)[tid] = 0;
    st0_sh[j0]     = st0[b * H_ + j0];
    st0_sh[j0 + 1] = st0[b * H_ + j0 + 1];
    __syncthreads();

    // dense t=0 recurrent input (st0 is real-valued), fp16 V
    float pre0 = 0.f, pre1 = 0.f;
    #pragma unroll 8
    for (int h = 0; h < H_; ++h) {
        const float s = st0_sh[h];
        const h2v v = *reinterpret_cast<const h2v*>(&Vh[(size_t)h * H_ + j0]);
        pre0 = fmaf(s, (float)v.x, pre0);
        pre1 = fmaf(s, (float)v.y, pre1);
    }

    // wx prefetch pipeline
    float2 wxp[PF_];
    #pragma unroll
    for (int i = 0; i < PF_; ++i)
        wxp[i] = *reinterpret_cast<const float2*>(&wxb[(size_t)i * H_ + j0]);

    int p = 0;
    for (int g = 0; g < T_ / PF_; ++g) {
        #pragma unroll
        for (int i = 0; i < PF_; ++i) {
            const int t = g * PF_ + i;
            const float2 wx = wxp[i];
            if (t + PF_ < T_)
                wxp[i] = *reinterpret_cast<const float2*>(&wxb[(size_t)(t + PF_) * H_ + j0]);

            // ---- gather over previous step's active list (fp16 rows) ----
            float rec0 = 0.f, rec1 = 0.f;
            #pragma unroll
            for (int seg = 0; seg < 4; ++seg) {
                const int n = __builtin_amdgcn_readfirstlane(cnt[p][seg]);
                const int* ap = &act[p][seg][0];
                int k = 0;
                for (; k + 4 <= n; k += 4) {
                    const int4 h4 = *reinterpret_cast<const int4*>(ap + k); // b128 broadcast
                    const h2v v0 = *reinterpret_cast<const h2v*>(&Vh[(size_t)h4.x * H_ + j0]);
                    const h2v v1 = *reinterpret_cast<const h2v*>(&Vh[(size_t)h4.y * H_ + j0]);
                    const h2v v2 = *reinterpret_cast<const h2v*>(&Vh[(size_t)h4.z * H_ + j0]);
                    const h2v v3 = *reinterpret_cast<const h2v*>(&Vh[(size_t)h4.w * H_ + j0]);
                    rec0 += ((float)v0.x + (float)v1.x) + ((float)v2.x + (float)v3.x);
                    rec1 += ((float)v0.y + (float)v1.y) + ((float)v2.y + (float)v3.y);
                }
                for (; k < n; ++k) {
                    const h2v v = *reinterpret_cast<const h2v*>(&Vh[(size_t)ap[k] * H_ + j0]);
                    rec0 += (float)v.x; rec1 += (float)v.y;
                }
            }
            if (t == 0) { rec0 = pre0; rec1 = pre1; }
            rec0 -= s0 * vd0;               // zero-diagonal correction (same fp16 values)
            rec1 -= s1 * vd1;

            u0 = a0 * (u0 - s0) + om0 * (wx.x + rec0);
            u1 = a1 * (u1 - s1) + om1 * (wx.y + rec1);
            s0 = (u0 > 1.f) ? 1.f : 0.f;
            s1 = (u1 > 1.f) ? 1.f : 0.f;
            f0 += s0; f1 += s1;
            *reinterpret_cast<float2*>(&sob[(size_t)t * H_ + j0]) = make_float2(s0, s1);

            // ---- build next step's list (ballot prefix, no atomics) ----
            const unsigned long long bal0 = __ballot(u0 > 1.f);
            const unsigned long long bal1 = __ballot(u1 > 1.f);
            const unsigned long long lt = (lane == 63) ? 0x7FFFFFFFFFFFFFFFULL
                                                       : ((1ULL << lane) - 1ULL);
            int k = (int)__popcll(bal0 & lt) + (int)__popcll(bal1 & lt);
            int* seg = &act[p ^ 1][wid][0];
            if (s0 != 0.f) { seg[k] = j0; ++k; }
            if (s1 != 0.f) { seg[k] = j0 + 1; }
            if (lane == 0) cnt[p ^ 1][wid] = (int)__popcll(bal0) + (int)__popcll(bal1);

            asm volatile("s_waitcnt lgkmcnt(0)" ::: "memory");
            __builtin_amdgcn_s_barrier();
            __builtin_amdgcn_sched_barrier(0);
            p ^= 1;
        }
    }
    fire[b * H_ + j0]     = f0;
    fire[b * H_ + j0 + 1] = f1;
}

// ------------------------------------------------------------------
// Readout, parallel-scan decomposition over T.
// ------------------------------------------------------------------
__global__ __launch_bounds__(256) void ro_partial_kernel(
    const float* __restrict__ Wx,    // [B,T,H]
    const float* __restrict__ alpha,
    float* __restrict__ u_end)       // [B,C,H]
{
    const int b = blockIdx.x;
    const int c = blockIdx.y;
    const int j0 = threadIdx.x * 2;
    const float a0 = clampAlpha(alpha[j0]);
    const float a1 = clampAlpha(alpha[j0 + 1]);
    const float om0 = 1.f - a0, om1 = 1.f - a1;
    float u0 = 0.f, u1 = 0.f;
    const float* wxb = Wx + ((size_t)b * T_ + (size_t)c * L_) * H_;
    #pragma unroll 4
    for (int t = 0; t < L_; ++t) {
        const float2 wx = *reinterpret_cast<const float2*>(&wxb[(size_t)t * H_ + j0]);
        u0 = fmaf(a0, u0, om0 * wx.x);
        u1 = fmaf(a1, u1, om1 * wx.y);
    }
    float* ue = u_end + ((size_t)b * C_ + c) * H_;
    *reinterpret_cast<float2*>(&ue[j0]) = make_float2(u0, u1);
}

__global__ __launch_bounds__(256) void ro_carry_kernel(
    const float* __restrict__ u_end, // [B,C,H]
    const float* __restrict__ alpha,
    const float* __restrict__ ut0,   // [B,H]
    float* __restrict__ carry)       // [B,C,H]
{
    const int b = blockIdx.x;
    const int j0 = threadIdx.x * 2;
    const float a0 = clampAlpha(alpha[j0]);
    const float a1 = clampAlpha(alpha[j0 + 1]);
    const float aL0 = powf(a0, (float)L_);
    const float aL1 = powf(a1, (float)L_);
    float c0 = ut0[b * H_ + j0];
    float c1 = ut0[b * H_ + j0 + 1];
    for (int c = 0; c < C_; ++c) {
        float* cr = carry + ((size_t)b * C_ + c) * H_;
        *reinterpret_cast<float2*>(&cr[j0]) = make_float2(c0, c1);
        const float2 ue = *reinterpret_cast<const float2*>(
            &u_end[((size_t)b * C_ + c) * H_ + j0]);
        c0 = fmaf(aL0, c0, ue.x);
        c1 = fmaf(aL1, c1, ue.y);
    }
}

__global__ __launch_bounds__(256) void ro_softmax_kernel(
    const float* __restrict__ Wx,    // [B,T,H]
    const float* __restrict__ alpha,
    const float* __restrict__ carry, // [B,C,H]
    float* __restrict__ opart)       // [C,B,H]
{
    const int b = blockIdx.x;
    const int c = blockIdx.y;
    const int tid = threadIdx.x;
    const int j0 = tid * 2;
    __shared__ float red[8];
    const float a0 = clampAlpha(alpha[j0]);
    const float a1 = clampAlpha(alpha[j0 + 1]);
    const float om0 = 1.f - a0, om1 = 1.f - a1;
    float2 u = *reinterpret_cast<const float2*>(
        &carry[((size_t)b * C_ + c) * H_ + j0]);
    float u0 = u.x, u1 = u.y;
    float o0 = 0.f, o1 = 0.f;
    const float* wxb = Wx + ((size_t)b * T_ + (size_t)c * L_) * H_;
    const int wave = tid >> 6;
    const int lane = tid & 63;

    for (int t = 0; t < L_; ++t) {
        const float2 wx = *reinterpret_cast<const float2*>(&wxb[(size_t)t * H_ + j0]);
        u0 = fmaf(a0, u0, om0 * wx.x);
        u1 = fmaf(a1, u1, om1 * wx.y);
        float m = fmaxf(u0, u1);
        #pragma unroll
        for (int off = 32; off > 0; off >>= 1)
            m = fmaxf(m, __shfl_xor(m, off, 64));
        if (lane == 0) red[wave] = m;
        __syncthreads();
        m = fmaxf(fmaxf(red[0], red[1]), fmaxf(red[2], red[3]));
        const float e0 = expf(u0 - m), e1 = expf(u1 - m);
        float sum = e0 + e1;
        #pragma unroll
        for (int off = 32; off > 0; off >>= 1)
            sum += __shfl_xor(sum, off, 64);
        if (lane == 0) red[4 + wave] = sum;
        __syncthreads();
        sum = (red[4] + red[5]) + (red[6] + red[7]);
        const float inv = 1.f / sum;
        o0 = fmaf(e0, inv, o0);
        o1 = fmaf(e1, inv, o1);
        __syncthreads();
    }
    float* op = opart + ((size_t)c * B_ + b) * H_;
    *reinterpret_cast<float2*>(&op[j0]) = make_float2(o0, o1);
}

__global__ __launch_bounds__(256) void ro_reduce_kernel(
    const float* __restrict__ opart, float* __restrict__ out)
{
    const int idx = blockIdx.x * 256 + threadIdx.x;  // 0 .. B*H-1
    float s = 0.f;
    for (int c = 0; c < C_; ++c) s += opart[(size_t)c * B_ * H_ + idx];
    out[idx] = s;
}

__global__ __launch_bounds__(256) void fire_reduce_kernel(
    const float* __restrict__ fire, float* __restrict__ out)
{
    const int h = blockIdx.x * 256 + threadIdx.x;
    if (h >= H_) return;
    const float inv = 1.f / (float)(B_ * T_);
    float s = 0.f;
    for (int b = 0; b < B_; ++b) s += fire[b * H_ + h];
    out[h] = s * inv;
    s = 0.f;
    for (int b = 0; b < B_; ++b) s += fire[B_ * H_ + b * H_ + h];
    out[H_ + h] = s * inv;
}

extern "C" void kernel_launch(void* const* d_in, const int* in_sizes, int n_in,
                              void* d_out, int out_size, void* d_ws, size_t ws_size,
                              hipStream_t stream)
{
    const float* x      = (const float*)d_in[0];
    const float* W0     = (const float*)d_in[1];
    const float* V0     = (const float*)d_in[2];
    const float* alpha0 = (const float*)d_in[3];
    const float* W1     = (const float*)d_in[4];
    const float* V1     = (const float*)d_in[5];
    const float* alpha1 = (const float*)d_in[6];
    const float* Wr     = (const float*)d_in[7];
    const float* alphar = (const float*)d_in[8];
    const float* ut0_0  = (const float*)d_in[9];
    const float* st0_0  = (const float*)d_in[10];
    const float* ut0_1  = (const float*)d_in[11];
    const float* st0_1  = (const float*)d_in[12];
    const float* ut0_r  = (const float*)d_in[13];
    float* out = (float*)d_out;

    const size_t NBTH = (size_t)B_ * T_ * H_;
    const size_t NBCH = (size_t)B_ * C_ * H_;
    float* buf0  = (float*)d_ws;          // Wx0 -> Wx1 -> Wxr
    float* buf1  = buf0 + NBTH;           // s0  -> s1
    float* fire  = buf1 + NBTH;           // [2, B, H]
    float* u_end = fire + 2 * B_ * H_;    // [B, C, H]
    float* carry = u_end + NBCH;          // [B, C, H]
    float* opart = carry + NBCH;          // [C, B, H]
    _Float16* V0h = (_Float16*)(opart + (size_t)C_ * B_ * H_);
    _Float16* V1h = V0h + (size_t)H_ * H_;

    // fp16 copies of the recurrent matrices
    vconv_kernel<<<(H_ * H_) / 1024, 256, 0, stream>>>(V0, V0h);
    vconv_kernel<<<(H_ * H_) / 1024, 256, 0, stream>>>(V1, V1h);

    dim3 gG(32000 / 64, 512 / 64);
    // Wx0 = x @ W0^T
    gemm_bt_kernel<<<gG, 256, 0, stream>>>(x, W0, buf0, 32000, 512, 700);
    // s0 = RLIF(Wx0, V0)
    rlif_kernel<<<32, 256, 0, stream>>>(buf0, V0h, alpha0, ut0_0, st0_0, buf1, fire);
    // Wx1 = s0 @ W1^T
    gemm_bt_kernel<<<gG, 256, 0, stream>>>(buf1, W1, buf0, 32000, 512, 512);
    // s1 = RLIF(Wx1, V1)
    rlif_kernel<<<32, 256, 0, stream>>>(buf0, V1h, alpha1, ut0_1, st0_1, buf1, fire + B_ * H_);
    // Wxr = s1 @ Wr^T
    gemm_bt_kernel<<<gG, 256, 0, stream>>>(buf1, Wr, buf0, 32000, 512, 512);
    // Readout: parallel scan + softmax partials + reduce
    ro_partial_kernel<<<dim3(B_, C_), 256, 0, stream>>>(buf0, alphar, u_end);
    ro_carry_kernel<<<B_, 256, 0, stream>>>(u_end, alphar, ut0_r, carry);
    ro_softmax_kernel<<<dim3(B_, C_), 256, 0, stream>>>(buf0, alphar, carry, opart);
    ro_reduce_kernel<<<(B_ * H_) / 256, 256, 0, stream>>>(opart, out);
    // firing rates
    fire_reduce_kernel<<<2, 256, 0, stream>>>(fire, out + B_ * H_);
}

// Round 6
// 1404.973 us; speedup vs baseline: 1.7143x; 1.2440x over previous
//
#include <hip/hip_runtime.h>

#define H_   512
#define T_   1000
#define B_   32
#define C_   50     // readout chunks
#define L_   20     // chunk length (C_*L_ == T_)
#define PF_  4      // wx prefetch depth / inner unroll

typedef _Float16 h2v __attribute__((ext_vector_type(2)));
typedef _Float16 h4v __attribute__((ext_vector_type(4)));

static __device__ __forceinline__ float clampAlpha(float a) {
    const float AMIN = 0.8187307530779818f;   // exp(-1/5)
    const float AMAX = 0.9607894391523232f;   // exp(-1/25)
    return fminf(fmaxf(a, AMIN), AMAX);
}

// ------------------------------------------------------------------
// fp32 -> fp16 copy (V matrices), 4 elems/thread
// ------------------------------------------------------------------
__global__ __launch_bounds__(256) void vconv_kernel(
    const float* __restrict__ V, _Float16* __restrict__ Vh)
{
    const int i = (blockIdx.x * 256 + threadIdx.x) * 4;
    const float4 v = *reinterpret_cast<const float4*>(V + i);
    h4v o;
    o.x = (_Float16)v.x; o.y = (_Float16)v.y;
    o.z = (_Float16)v.z; o.w = (_Float16)v.w;
    *reinterpret_cast<h4v*>(Vh + i) = o;
}

// ------------------------------------------------------------------
// Wt[h][g] = (fp16) W[g][h]  -- transpose+convert, 32x32 LDS tiles
// ------------------------------------------------------------------
__global__ __launch_bounds__(256) void tconv_kernel(
    const float* __restrict__ W, _Float16* __restrict__ Wt)
{
    __shared__ float tile[32][33];
    const int bx = blockIdx.x * 32, by = blockIdx.y * 32;
    const int tx = threadIdx.x & 31, ty = threadIdx.x >> 5;   // 32 x 8
    #pragma unroll
    for (int r = 0; r < 32; r += 8)
        tile[ty + r][tx] = W[(size_t)(by + ty + r) * H_ + bx + tx];
    __syncthreads();
    #pragma unroll
    for (int r = 0; r < 32; r += 8)
        Wt[(size_t)(bx + ty + r) * H_ + by + tx] = (_Float16)tile[tx][ty + r];
}

// ------------------------------------------------------------------
// C[m,n] = sum_k A[m,k] * Bt[n,k]   (dense input GEMM, layer 0 only)
// ------------------------------------------------------------------
__global__ __launch_bounds__(256) void gemm_bt_kernel(
    const float* __restrict__ A, const float* __restrict__ Bt,
    float* __restrict__ C, int M, int N, int K)
{
    __shared__ __align__(16) float As[16][68];
    __shared__ __align__(16) float Bs[16][68];
    const int tid = threadIdx.x;
    const int bm = blockIdx.x * 64;
    const int bn = blockIdx.y * 64;
    const int tx = tid & 15, ty = tid >> 4;
    const int lrow = tid >> 2;
    const int lk   = (tid & 3) << 2;
    float acc[4][4] = {};
    const float* Arow = A + (size_t)(bm + lrow) * K;
    const float* Brow = Bt + (size_t)(bn + lrow) * K;

    for (int k0 = 0; k0 < K; k0 += 16) {
        const int ka = k0 + lk;
        float4 av, bv;
        if (ka + 3 < K) {
            av = *reinterpret_cast<const float4*>(Arow + ka);
            bv = *reinterpret_cast<const float4*>(Brow + ka);
        } else {
            float a_[4], b_[4];
            #pragma unroll
            for (int i = 0; i < 4; ++i) {
                a_[i] = (ka + i < K) ? Arow[ka + i] : 0.f;
                b_[i] = (ka + i < K) ? Brow[ka + i] : 0.f;
            }
            av = make_float4(a_[0], a_[1], a_[2], a_[3]);
            bv = make_float4(b_[0], b_[1], b_[2], b_[3]);
        }
        __syncthreads();
        As[lk + 0][lrow] = av.x; As[lk + 1][lrow] = av.y;
        As[lk + 2][lrow] = av.z; As[lk + 3][lrow] = av.w;
        Bs[lk + 0][lrow] = bv.x; Bs[lk + 1][lrow] = bv.y;
        Bs[lk + 2][lrow] = bv.z; Bs[lk + 3][lrow] = bv.w;
        __syncthreads();
        #pragma unroll
        for (int kk = 0; kk < 16; ++kk) {
            const float4 a4 = *reinterpret_cast<const float4*>(&As[kk][ty << 2]);
            const float4 b4 = *reinterpret_cast<const float4*>(&Bs[kk][tx << 2]);
            const float aa[4] = {a4.x, a4.y, a4.z, a4.w};
            const float bb[4] = {b4.x, b4.y, b4.z, b4.w};
            #pragma unroll
            for (int i = 0; i < 4; ++i)
                #pragma unroll
                for (int j = 0; j < 4; ++j)
                    acc[i][j] = fmaf(aa[i], bb[j], acc[i][j]);
        }
    }
    #pragma unroll
    for (int i = 0; i < 4; ++i) {
        const float4 r = make_float4(acc[i][0], acc[i][1], acc[i][2], acc[i][3]);
        *reinterpret_cast<float4*>(&C[(size_t)(bm + ty * 4 + i) * N + bn + tx * 4]) = r;
    }
}

// ------------------------------------------------------------------
// Fused SNN core: layer0 RLIF + W1^T gather + layer1 RLIF + Wr^T
// gather, software-pipelined stagger: iteration i computes s0_i,
// s1_{i-1}, stores Wxr_{i-2}. All four gathers depend only on the
// active lists published at the previous barrier -> they issue in
// parallel; ONE raw s_barrier per iteration (lgkmcnt-only).
// ------------------------------------------------------------------
__global__ __launch_bounds__(256) void fused_snn_kernel(
    const float* __restrict__ Wx0,      // [B,T,H]
    const _Float16* __restrict__ V0h,   // [H,H]
    const _Float16* __restrict__ W1th,  // [H,H]  W1th[h][g] = W1[g][h]
    const _Float16* __restrict__ V1h,   // [H,H]
    const _Float16* __restrict__ Wrth,  // [H,H]  Wrth[h][g] = Wr[g][h]
    const float* __restrict__ alpha0, const float* __restrict__ alpha1,
    const float* __restrict__ ut00, const float* __restrict__ st00,
    const float* __restrict__ ut01, const float* __restrict__ st01,
    float* __restrict__ wxr,            // [B,T,H] readout drive out
    float* __restrict__ fire)           // [2,B,H] spike counts
{
    const int b    = blockIdx.x;
    const int tid  = threadIdx.x;       // 0..255
    const int j0   = tid * 2;
    const int wid  = tid >> 6;
    const int lane = tid & 63;
    __shared__ __align__(16) int act0[2][4][132];
    __shared__ __align__(16) int act1[2][4][132];
    __shared__ int cnt0[2][4];
    __shared__ int cnt1[2][4];
    __shared__ float sh[H_];

    const float a0a = clampAlpha(alpha0[j0]);
    const float a0b = clampAlpha(alpha0[j0 + 1]);
    const float om0a = 1.f - a0a, om0b = 1.f - a0b;
    const float a1a = clampAlpha(alpha1[j0]);
    const float a1b = clampAlpha(alpha1[j0 + 1]);
    const float om1a = 1.f - a1a, om1b = 1.f - a1b;
    const float vd0a = (float)V0h[(size_t)j0 * H_ + j0];
    const float vd0b = (float)V0h[(size_t)(j0 + 1) * H_ + j0 + 1];
    const float vd1a = (float)V1h[(size_t)j0 * H_ + j0];
    const float vd1b = (float)V1h[(size_t)(j0 + 1) * H_ + j0 + 1];

    float u0a = ut00[b * H_ + j0], u0b = ut00[b * H_ + j0 + 1];
    float s0a = st00[b * H_ + j0], s0b = st00[b * H_ + j0 + 1];
    float u1a = ut01[b * H_ + j0], u1b = ut01[b * H_ + j0 + 1];
    float s1a = st01[b * H_ + j0], s1b = st01[b * H_ + j0 + 1];
    float f0a = 0.f, f0b = 0.f, f1a = 0.f, f1b = 0.f;

    const float* wxb  = Wx0 + (size_t)b * T_ * H_;
    float*       wxrb = wxr + (size_t)b * T_ * H_;

    // zero both parities of both count arrays
    if (tid < 8)               ((int*)cnt0)[tid] = 0;
    if (tid >= 8 && tid < 16)  ((int*)cnt1)[tid - 8] = 0;

    // dense t=0 recurrent pre-passes (st0 real-valued)
    sh[j0] = s0a; sh[j0 + 1] = s0b;
    __syncthreads();
    float pre0a = 0.f, pre0b = 0.f;
    #pragma unroll 8
    for (int h = 0; h < H_; ++h) {
        const float s = sh[h];
        const h2v v = *reinterpret_cast<const h2v*>(&V0h[(size_t)h * H_ + j0]);
        pre0a = fmaf(s, (float)v.x, pre0a);
        pre0b = fmaf(s, (float)v.y, pre0b);
    }
    __syncthreads();
    sh[j0] = s1a; sh[j0 + 1] = s1b;
    __syncthreads();
    float pre1a = 0.f, pre1b = 0.f;
    #pragma unroll 8
    for (int h = 0; h < H_; ++h) {
        const float s = sh[h];
        const h2v v = *reinterpret_cast<const h2v*>(&V1h[(size_t)h * H_ + j0]);
        pre1a = fmaf(s, (float)v.x, pre1a);
        pre1b = fmaf(s, (float)v.y, pre1b);
    }
    __syncthreads();

    // wx0 prefetch pipeline
    float2 wxp[PF_];
    #pragma unroll
    for (int i = 0; i < PF_; ++i)
        wxp[i] = *reinterpret_cast<const float2*>(&wxb[(size_t)i * H_ + j0]);

    int p = 0;
    for (int g = 0; g < (T_ + 2 + PF_ - 1) / PF_; ++g) {
        #pragma unroll
        for (int i4 = 0; i4 < PF_; ++i4) {
            const int i = g * PF_ + i4;
            if (i > T_ + 1) break;       // uniform

            // ---- gathers over published lists (all independent) ----
            float r0a = 0.f, r0b = 0.f, w1a = 0.f, w1b = 0.f;
            #pragma unroll
            for (int seg = 0; seg < 4; ++seg) {
                const int n = __builtin_amdgcn_readfirstlane(cnt0[p][seg]);
                const int* ap = &act0[p][seg][0];
                int k = 0;
                for (; k + 4 <= n; k += 4) {
                    const int4 h4 = *reinterpret_cast<const int4*>(ap + k);
                    const h2v va = *reinterpret_cast<const h2v*>(&V0h[(size_t)h4.x * H_ + j0]);
                    const h2v vb = *reinterpret_cast<const h2v*>(&V0h[(size_t)h4.y * H_ + j0]);
                    const h2v vc = *reinterpret_cast<const h2v*>(&V0h[(size_t)h4.z * H_ + j0]);
                    const h2v vdd = *reinterpret_cast<const h2v*>(&V0h[(size_t)h4.w * H_ + j0]);
                    const h2v wa = *reinterpret_cast<const h2v*>(&W1th[(size_t)h4.x * H_ + j0]);
                    const h2v wb = *reinterpret_cast<const h2v*>(&W1th[(size_t)h4.y * H_ + j0]);
                    const h2v wc = *reinterpret_cast<const h2v*>(&W1th[(size_t)h4.z * H_ + j0]);
                    const h2v wdd = *reinterpret_cast<const h2v*>(&W1th[(size_t)h4.w * H_ + j0]);
                    r0a += ((float)va.x + (float)vb.x) + ((float)vc.x + (float)vdd.x);
                    r0b += ((float)va.y + (float)vb.y) + ((float)vc.y + (float)vdd.y);
                    w1a += ((float)wa.x + (float)wb.x) + ((float)wc.x + (float)wdd.x);
                    w1b += ((float)wa.y + (float)wb.y) + ((float)wc.y + (float)wdd.y);
                }
                for (; k < n; ++k) {
                    const int h = ap[k];
                    const h2v v = *reinterpret_cast<const h2v*>(&V0h[(size_t)h * H_ + j0]);
                    const h2v w = *reinterpret_cast<const h2v*>(&W1th[(size_t)h * H_ + j0]);
                    r0a += (float)v.x; r0b += (float)v.y;
                    w1a += (float)w.x; w1b += (float)w.y;
                }
            }
            float r1a = 0.f, r1b = 0.f, wra = 0.f, wrb = 0.f;
            #pragma unroll
            for (int seg = 0; seg < 4; ++seg) {
                const int n = __builtin_amdgcn_readfirstlane(cnt1[p][seg]);
                const int* ap = &act1[p][seg][0];
                int k = 0;
                for (; k + 4 <= n; k += 4) {
                    const int4 h4 = *reinterpret_cast<const int4*>(ap + k);
                    const h2v va = *reinterpret_cast<const h2v*>(&V1h[(size_t)h4.x * H_ + j0]);
                    const h2v vb = *reinterpret_cast<const h2v*>(&V1h[(size_t)h4.y * H_ + j0]);
                    const h2v vc = *reinterpret_cast<const h2v*>(&V1h[(size_t)h4.z * H_ + j0]);
                    const h2v vdd = *reinterpret_cast<const h2v*>(&V1h[(size_t)h4.w * H_ + j0]);
                    const h2v wa = *reinterpret_cast<const h2v*>(&Wrth[(size_t)h4.x * H_ + j0]);
                    const h2v wb = *reinterpret_cast<const h2v*>(&Wrth[(size_t)h4.y * H_ + j0]);
                    const h2v wc = *reinterpret_cast<const h2v*>(&Wrth[(size_t)h4.z * H_ + j0]);
                    const h2v wdd = *reinterpret_cast<const h2v*>(&Wrth[(size_t)h4.w * H_ + j0]);
                    r1a += ((float)va.x + (float)vb.x) + ((float)vc.x + (float)vdd.x);
                    r1b += ((float)va.y + (float)vb.y) + ((float)vc.y + (float)vdd.y);
                    wra += ((float)wa.x + (float)wb.x) + ((float)wc.x + (float)wdd.x);
                    wrb += ((float)wa.y + (float)wb.y) + ((float)wc.y + (float)wdd.y);
                }
                for (; k < n; ++k) {
                    const int h = ap[k];
                    const h2v v = *reinterpret_cast<const h2v*>(&V1h[(size_t)h * H_ + j0]);
                    const h2v w = *reinterpret_cast<const h2v*>(&Wrth[(size_t)h * H_ + j0]);
                    r1a += (float)v.x; r1b += (float)v.y;
                    wra += (float)w.x; wrb += (float)w.y;
                }
            }

            // ---- layer0 update (t0 = i) ----
            if (i < T_) {
                const float2 wx = wxp[i4];
                if (i + PF_ < T_)
                    wxp[i4] = *reinterpret_cast<const float2*>(&wxb[(size_t)(i + PF_) * H_ + j0]);
                if (i == 0) { r0a = pre0a; r0b = pre0b; }
                r0a -= s0a * vd0a; r0b -= s0b * vd0b;
                u0a = a0a * (u0a - s0a) + om0a * (wx.x + r0a);
                u0b = a0b * (u0b - s0b) + om0b * (wx.y + r0b);
                s0a = (u0a > 1.f) ? 1.f : 0.f;
                s0b = (u0b > 1.f) ? 1.f : 0.f;
                f0a += s0a; f0b += s0b;
                const unsigned long long ba = __ballot(u0a > 1.f);
                const unsigned long long bb = __ballot(u0b > 1.f);
                const unsigned long long lt = (lane == 63) ? 0x7FFFFFFFFFFFFFFFULL
                                                           : ((1ULL << lane) - 1ULL);
                int k = (int)__popcll(ba & lt) + (int)__popcll(bb & lt);
                int* sp = &act0[p ^ 1][wid][0];
                if (s0a != 0.f) { sp[k] = j0; ++k; }
                if (s0b != 0.f) { sp[k] = j0 + 1; }
                if (lane == 0) cnt0[p ^ 1][wid] = (int)__popcll(ba) + (int)__popcll(bb);
            }
            // ---- layer1 update (t1 = i-1) ----
            if (i >= 1 && i <= T_) {
                if (i == 1) { r1a = pre1a; r1b = pre1b; }
                r1a -= s1a * vd1a; r1b -= s1b * vd1b;
                u1a = a1a * (u1a - s1a) + om1a * (w1a + r1a);
                u1b = a1b * (u1b - s1b) + om1b * (w1b + r1b);
                s1a = (u1a > 1.f) ? 1.f : 0.f;
                s1b = (u1b > 1.f) ? 1.f : 0.f;
                f1a += s1a; f1b += s1b;
                const unsigned long long ba = __ballot(u1a > 1.f);
                const unsigned long long bb = __ballot(u1b > 1.f);
                const unsigned long long lt = (lane == 63) ? 0x7FFFFFFFFFFFFFFFULL
                                                           : ((1ULL << lane) - 1ULL);
                int k = (int)__popcll(ba & lt) + (int)__popcll(bb & lt);
                int* sp = &act1[p ^ 1][wid][0];
                if (s1a != 0.f) { sp[k] = j0; ++k; }
                if (s1b != 0.f) { sp[k] = j0 + 1; }
                if (lane == 0) cnt1[p ^ 1][wid] = (int)__popcll(ba) + (int)__popcll(bb);
            }
            // ---- readout drive store (tr = i-2) ----
            if (i >= 2)
                *reinterpret_cast<float2*>(&wxrb[(size_t)(i - 2) * H_ + j0]) =
                    make_float2(wra, wrb);

            asm volatile("s_waitcnt lgkmcnt(0)" ::: "memory");
            __builtin_amdgcn_s_barrier();
            __builtin_amdgcn_sched_barrier(0);
            p ^= 1;
        }
    }
    fire[b * H_ + j0]               = f0a;
    fire[b * H_ + j0 + 1]           = f0b;
    fire[B_ * H_ + b * H_ + j0]     = f1a;
    fire[B_ * H_ + b * H_ + j0 + 1] = f1b;
}

// ------------------------------------------------------------------
// Readout, parallel-scan decomposition over T (unchanged).
// ------------------------------------------------------------------
__global__ __launch_bounds__(256) void ro_partial_kernel(
    const float* __restrict__ Wx, const float* __restrict__ alpha,
    float* __restrict__ u_end)
{
    const int b = blockIdx.x;
    const int c = blockIdx.y;
    const int j0 = threadIdx.x * 2;
    const float a0 = clampAlpha(alpha[j0]);
    const float a1 = clampAlpha(alpha[j0 + 1]);
    const float om0 = 1.f - a0, om1 = 1.f - a1;
    float u0 = 0.f, u1 = 0.f;
    const float* wxb = Wx + ((size_t)b * T_ + (size_t)c * L_) * H_;
    #pragma unroll 4
    for (int t = 0; t < L_; ++t) {
        const float2 wx = *reinterpret_cast<const float2*>(&wxb[(size_t)t * H_ + j0]);
        u0 = fmaf(a0, u0, om0 * wx.x);
        u1 = fmaf(a1, u1, om1 * wx.y);
    }
    float* ue = u_end + ((size_t)b * C_ + c) * H_;
    *reinterpret_cast<float2*>(&ue[j0]) = make_float2(u0, u1);
}

__global__ __launch_bounds__(256) void ro_carry_kernel(
    const float* __restrict__ u_end, const float* __restrict__ alpha,
    const float* __restrict__ ut0, float* __restrict__ carry)
{
    const int b = blockIdx.x;
    const int j0 = threadIdx.x * 2;
    const float a0 = clampAlpha(alpha[j0]);
    const float a1 = clampAlpha(alpha[j0 + 1]);
    const float aL0 = powf(a0, (float)L_);
    const float aL1 = powf(a1, (float)L_);
    float c0 = ut0[b * H_ + j0];
    float c1 = ut0[b * H_ + j0 + 1];
    for (int c = 0; c < C_; ++c) {
        float* cr = carry + ((size_t)b * C_ + c) * H_;
        *reinterpret_cast<float2*>(&cr[j0]) = make_float2(c0, c1);
        const float2 ue = *reinterpret_cast<const float2*>(
            &u_end[((size_t)b * C_ + c) * H_ + j0]);
        c0 = fmaf(aL0, c0, ue.x);
        c1 = fmaf(aL1, c1, ue.y);
    }
}

__global__ __launch_bounds__(256) void ro_softmax_kernel(
    const float* __restrict__ Wx, const float* __restrict__ alpha,
    const float* __restrict__ carry, float* __restrict__ opart)
{
    const int b = blockIdx.x;
    const int c = blockIdx.y;
    const int tid = threadIdx.x;
    const int j0 = tid * 2;
    __shared__ float red[8];
    const float a0 = clampAlpha(alpha[j0]);
    const float a1 = clampAlpha(alpha[j0 + 1]);
    const float om0 = 1.f - a0, om1 = 1.f - a1;
    float2 u = *reinterpret_cast<const float2*>(
        &carry[((size_t)b * C_ + c) * H_ + j0]);
    float u0 = u.x, u1 = u.y;
    float o0 = 0.f, o1 = 0.f;
    const float* wxb = Wx + ((size_t)b * T_ + (size_t)c * L_) * H_;
    const int wave = tid >> 6;
    const int lane = tid & 63;

    for (int t = 0; t < L_; ++t) {
        const float2 wx = *reinterpret_cast<const float2*>(&wxb[(size_t)t * H_ + j0]);
        u0 = fmaf(a0, u0, om0 * wx.x);
        u1 = fmaf(a1, u1, om1 * wx.y);
        float m = fmaxf(u0, u1);
        #pragma unroll
        for (int off = 32; off > 0; off >>= 1)
            m = fmaxf(m, __shfl_xor(m, off, 64));
        if (lane == 0) red[wave] = m;
        __syncthreads();
        m = fmaxf(fmaxf(red[0], red[1]), fmaxf(red[2], red[3]));
        const float e0 = expf(u0 - m), e1 = expf(u1 - m);
        float sum = e0 + e1;
        #pragma unroll
        for (int off = 32; off > 0; off >>= 1)
            sum += __shfl_xor(sum, off, 64);
        if (lane == 0) red[4 + wave] = sum;
        __syncthreads();
        sum = (red[4] + red[5]) + (red[6] + red[7]);
        const float inv = 1.f / sum;
        o0 = fmaf(e0, inv, o0);
        o1 = fmaf(e1, inv, o1);
        __syncthreads();
    }
    float* op = opart + ((size_t)c * B_ + b) * H_;
    *reinterpret_cast<float2*>(&op[j0]) = make_float2(o0, o1);
}

__global__ __launch_bounds__(256) void ro_reduce_kernel(
    const float* __restrict__ opart, float* __restrict__ out)
{
    const int idx = blockIdx.x * 256 + threadIdx.x;
    float s = 0.f;
    for (int c = 0; c < C_; ++c) s += opart[(size_t)c * B_ * H_ + idx];
    out[idx] = s;
}

__global__ __launch_bounds__(256) void fire_reduce_kernel(
    const float* __restrict__ fire, float* __restrict__ out)
{
    const int h = blockIdx.x * 256 + threadIdx.x;
    if (h >= H_) return;
    const float inv = 1.f / (float)(B_ * T_);
    float s = 0.f;
    for (int b = 0; b < B_; ++b) s += fire[b * H_ + h];
    out[h] = s * inv;
    s = 0.f;
    for (int b = 0; b < B_; ++b) s += fire[B_ * H_ + b * H_ + h];
    out[H_ + h] = s * inv;
}

extern "C" void kernel_launch(void* const* d_in, const int* in_sizes, int n_in,
                              void* d_out, int out_size, void* d_ws, size_t ws_size,
                              hipStream_t stream)
{
    const float* x      = (const float*)d_in[0];
    const float* W0     = (const float*)d_in[1];
    const float* V0     = (const float*)d_in[2];
    const float* alpha0 = (const float*)d_in[3];
    const float* W1     = (const float*)d_in[4];
    const float* V1     = (const float*)d_in[5];
    const float* alpha1 = (const float*)d_in[6];
    const float* Wr     = (const float*)d_in[7];
    const float* alphar = (const float*)d_in[8];
    const float* ut0_0  = (const float*)d_in[9];
    const float* st0_0  = (const float*)d_in[10];
    const float* ut0_1  = (const float*)d_in[11];
    const float* st0_1  = (const float*)d_in[12];
    const float* ut0_r  = (const float*)d_in[13];
    float* out = (float*)d_out;

    const size_t NBTH = (size_t)B_ * T_ * H_;
    const size_t NBCH = (size_t)B_ * C_ * H_;
    float* buf0 = (float*)d_ws;                   // Wx0 (dead after fused)
    float* buf1 = buf0 + NBTH;                    // Wxr
    float* fire = buf1 + NBTH;                    // [2,B,H]
    _Float16* V0h  = (_Float16*)(fire + 2 * B_ * H_);
    _Float16* V1h  = V0h + (size_t)H_ * H_;
    _Float16* W1th = V1h + (size_t)H_ * H_;
    _Float16* Wrth = W1th + (size_t)H_ * H_;
    // readout scratch aliases buf0 (Wx0 is dead once fused kernel ends)
    float* u_end = buf0;
    float* carry = u_end + NBCH;
    float* opart = carry + NBCH;

    // prep: fp16 V copies + fp16 transposed W1/Wr
    vconv_kernel<<<(H_ * H_) / 1024, 256, 0, stream>>>(V0, V0h);
    vconv_kernel<<<(H_ * H_) / 1024, 256, 0, stream>>>(V1, V1h);
    tconv_kernel<<<dim3(16, 16), 256, 0, stream>>>(W1, W1th);
    tconv_kernel<<<dim3(16, 16), 256, 0, stream>>>(Wr, Wrth);

    // Wx0 = x @ W0^T  (only dense GEMM left)
    dim3 gG(32000 / 64, 512 / 64);
    gemm_bt_kernel<<<gG, 256, 0, stream>>>(x, W0, buf0, 32000, 512, 700);

    // fused: layer0 + W1 gather + layer1 + Wr gather -> Wxr, fire
    fused_snn_kernel<<<32, 256, 0, stream>>>(
        buf0, V0h, W1th, V1h, Wrth, alpha0, alpha1,
        ut0_0, st0_0, ut0_1, st0_1, buf1, fire);

    // readout parallel scan on Wxr
    ro_partial_kernel<<<dim3(B_, C_), 256, 0, stream>>>(buf1, alphar, u_end);
    ro_carry_kernel<<<B_, 256, 0, stream>>>(u_end, alphar, ut0_r, carry);
    ro_softmax_kernel<<<dim3(B_, C_), 256, 0, stream>>>(buf1, alphar, carry, opart);
    ro_reduce_kernel<<<(B_ * H_) / 256, 256, 0, stream>>>(opart, out);
    fire_reduce_kernel<<<2, 256, 0, stream>>>(fire, out + B_ * H_);
}